// Round 2
// baseline (53828.632 us; speedup 1.0000x reference)
//
#include <hip/hip_runtime.h>
#include <hip/hip_bf16.h>
#include <stdint.h>

// ---------------------------------------------------------------------------
// Persistent-kernel LSTM decoder for MI355X.
// superphase s: g1 blocks: gates1[s] -> h1[s];  g2 blocks: gates2[s-1] -> h2[s-1];
//               fc blocks: fc partials on h2[s-2]; fcred blocks: frame[s-3] -> out.
// h1/h2 cross-XCD via MALL (sc0 sc1 stores + coherent global_load_lds aux=17).
// ---------------------------------------------------------------------------

#define NSUP 2003

typedef __attribute__((ext_vector_type(8))) short bf16x8;
typedef __attribute__((ext_vector_type(4))) float f32x4;

typedef const __attribute__((address_space(1))) unsigned int* GPTR;
typedef __attribute__((address_space(3))) unsigned int* LPTR;

// ws layout (bytes)
#define OFF_WTXT   0ull
#define OFF_WHH1   8388608ull
#define OFF_WPREV  16777216ull
#define OFF_WIH2   17825792ull
#define OFF_WHH2   26214400ull
#define OFF_FCW    34603008ull
#define OFF_BIAS2  34799616ull
#define OFF_PSTYLE 34816000ull
#define OFF_ENC    36913152ull
#define OFF_PREV   141770752ull
#define OFF_H1     207306752ull
#define OFF_H2     207831040ull
#define OFF_FCPART 208355328ull
#define OFF_CNT    208551936ull
#define OFF_STYLET 208553984ull
#define WS_NEED    208717824ull

__device__ __forceinline__ unsigned short f2bf(float f) {
  __hip_bfloat16 b = __float2bfloat16(f);
  return *reinterpret_cast<unsigned short*>(&b);
}
__device__ __forceinline__ float sigm(float x) { return 1.f / (1.f + __expf(-x)); }
__device__ __forceinline__ float tanh_(float x) {
  x = fminf(15.f, fmaxf(-15.f, x));
  float e = __expf(2.f * x);
  return (e - 1.f) / (e + 1.f);
}
// permuted gate-row -> original row (unit-major interleave of i,f,g,o)
__device__ __forceinline__ int origRow(int rp) {
  return ((rp >> 4) & 3) * 1024 + (rp >> 6) * 16 + (rp & 15);
}

// ------------------------------- pack kernels -------------------------------
__global__ void k_pack_w1(const float* __restrict__ wih1, const float* __restrict__ whh1,
                          unsigned char* __restrict__ ws) {
  int idx = blockIdx.x * 256 + threadIdx.x;            // 4096*1024
  int rp = idx >> 10, k = idx & 1023;
  int orig = origRow(rp);
  ((unsigned short*)(ws + OFF_WTXT))[idx] = f2bf(wih1[(size_t)orig * 1424 + k]);
  ((unsigned short*)(ws + OFF_WHH1))[idx] = f2bf(whh1[(size_t)orig * 1024 + k]);
}
__global__ void k_pack_w2(const float* __restrict__ wih2, const float* __restrict__ whh2,
                          unsigned char* __restrict__ ws) {
  int idx = blockIdx.x * 256 + threadIdx.x;
  int rp = idx >> 10, k = idx & 1023;
  int orig = origRow(rp);
  ((unsigned short*)(ws + OFF_WIH2))[idx] = f2bf(wih2[(size_t)orig * 1024 + k]);
  ((unsigned short*)(ws + OFF_WHH2))[idx] = f2bf(whh2[(size_t)orig * 1024 + k]);
}
__global__ void k_bias2(const float* __restrict__ bih2, const float* __restrict__ bhh2,
                        unsigned char* __restrict__ ws) {
  int rp = blockIdx.x * 256 + threadIdx.x;
  if (rp >= 4096) return;
  int orig = origRow(rp);
  ((float*)(ws + OFF_BIAS2))[rp] = bih2[orig] + bhh2[orig];
}
__global__ void k_pack_wprev(const float* __restrict__ wih1, unsigned char* __restrict__ ws) {
  int idx = blockIdx.x * 256 + threadIdx.x;            // 4096*128
  int rp = idx >> 7, k = idx & 127;
  int orig = origRow(rp);
  ((unsigned short*)(ws + OFF_WPREV))[idx] =
      (k < 80) ? f2bf(wih1[(size_t)orig * 1424 + 1344 + k]) : (unsigned short)0;
}
__global__ void k_pack_fc(const float* __restrict__ fcw, unsigned char* __restrict__ ws) {
  int idx = blockIdx.x * 256 + threadIdx.x;            // 96*1024
  int r = idx >> 10, k = idx & 1023;
  ((unsigned short*)(ws + OFF_FCW))[idx] =
      (r < 80) ? f2bf(fcw[(size_t)r * 1024 + k]) : (unsigned short)0;
}
__global__ void k_pack_enc(const float* __restrict__ enc, unsigned char* __restrict__ ws) {
  size_t i = (size_t)blockIdx.x * 256 + threadIdx.x;   // 13,107,200 float4's
  float4 v = ((const float4*)enc)[i];
  union { unsigned short u[4]; unsigned long long ll; } z;
  z.u[0] = f2bf(v.x); z.u[1] = f2bf(v.y); z.u[2] = f2bf(v.z); z.u[3] = f2bf(v.w);
  ((unsigned long long*)(ws + OFF_ENC))[i] = z.ll;
}
__global__ void k_styleT(const float* __restrict__ style, float* __restrict__ sT) {
  int idx = blockIdx.x * 256 + threadIdx.x;            // 320*128
  int j = idx >> 7, n = idx & 127;
  sT[idx] = style[n * 320 + j];
}
__global__ void k_pstyle(const float* __restrict__ wih1, const float* __restrict__ bih1,
                         const float* __restrict__ bhh1, const float* __restrict__ sT,
                         unsigned char* __restrict__ ws) {
  int n = threadIdx.x & 127, rsub = threadIdx.x >> 7;
  int rp = blockIdx.x * 2 + rsub;
  int orig = origRow(rp);
  const float* wr = wih1 + (size_t)orig * 1424 + 1024;
  float a0 = 0.f, a1 = 0.f, a2 = 0.f, a3 = 0.f;
  for (int j = 0; j < 320; j += 4) {
    a0 += wr[j + 0] * sT[(j + 0) * 128 + n];
    a1 += wr[j + 1] * sT[(j + 1) * 128 + n];
    a2 += wr[j + 2] * sT[(j + 2) * 128 + n];
    a3 += wr[j + 3] * sT[(j + 3) * 128 + n];
  }
  ((float*)(ws + OFF_PSTYLE))[rp * 128 + n] = (a0 + a1) + (a2 + a3) + bih1[orig] + bhh1[orig];
}
__global__ void k_pack_prev(const float* __restrict__ mel, unsigned char* __restrict__ ws) {
  __shared__ unsigned short pl[64][80];
  int b = blockIdx.y, tt0 = blockIdx.x * 64;
  int tid = threadIdx.x;
  int ttl = tid & 63, mi = tid >> 6;
  for (int m = mi; m < 80; m += 4) {
    int tau = tt0 + ttl;
    if (tau <= 1998) pl[ttl][m] = f2bf(mel[((size_t)b * 80 + m) * 2000 + tau]);
  }
  __syncthreads();
  unsigned short* pv = (unsigned short*)(ws + OFF_PREV);
  for (int idx = tid; idx < 64 * 80; idx += 256) {
    int t2 = idx / 80, m2 = idx % 80;
    int tau = tt0 + t2;
    if (tau <= 1998) pv[((size_t)(tau + 1) * 128 + b) * 128 + m2] = pl[t2][m2];
  }
}

// ------------------------------ persistent kernel ---------------------------
__global__ __launch_bounds__(256, 1) void k_persist(unsigned char* __restrict__ ws,
                                                    float* __restrict__ out,
                                                    const float* __restrict__ fc_b) {
  __shared__ __align__(1024) unsigned char smem[131072];  // 4 x (A16K + B16K) staging; epilogue aliases
  const int tid = threadIdx.x, bid = blockIdx.x;
  const int w = tid >> 6, l = tid & 63;
  const bool isG1 = bid < 128;
  const int lb = bid & 127, rb = lb >> 1, cg = lb & 1;
  const int rf = rb >> 1, khf = rb & 1;                   // fc sub-job coords (rb<10)
  const int r15 = l & 15;
  // XOR-swizzled lane offset for A/B fragment ds_read_b128 (2-bit key, within 64B row)
  const int laneOff = r15 * 64 + (((l >> 4) * 16) ^ (((r15 >> 1) & 3) << 4));

  const unsigned char* wA1 = ws + (isG1 ? OFF_WTXT : OFF_WIH2) + (size_t)(rb * 64) * 2048;
  const unsigned char* wA2 = ws + (isG1 ? OFF_WHH1 : OFF_WHH2) + (size_t)(rb * 64) * 2048;
  const unsigned char* wAp = ws + OFF_WPREV + (size_t)(rb * 64) * 256;
  const unsigned char* wFc = ws + OFF_FCW + (size_t)(rf * 16) * 2048;
  const unsigned char* encB = ws + OFF_ENC + (size_t)(cg * 64) * 819200;
  const unsigned char* prevB = ws + OFF_PREV + (size_t)(cg * 64) * 256;
  unsigned short* h1buf = (unsigned short*)(ws + OFF_H1);
  unsigned short* h2buf = (unsigned short*)(ws + OFF_H2);
  float* fcpart = (float*)(ws + OFF_FCPART);
  unsigned* cnts = (unsigned*)(ws + OFF_CNT);

  // hoisted epilogue constants (constant over all steps)
  const int eu = tid >> 4;          // unit 0..15 within tile
  const int ec0 = (tid & 15) << 2;  // col offset 0..60
  float pst[4][4];
  float b2r[4] = {0, 0, 0, 0};
  if (isG1) {
    const float* PS = (const float*)(ws + OFF_PSTYLE);
#pragma unroll
    for (int g = 0; g < 4; ++g)
#pragma unroll
      for (int cc = 0; cc < 4; ++cc)
        pst[g][cc] = PS[(size_t)(rb * 64 + 16 * g + eu) * 128 + cg * 64 + ec0 + cc];
  } else {
    const float* B2 = (const float*)(ws + OFF_BIAS2);
#pragma unroll
    for (int g = 0; g < 4; ++g) b2r[g] = B2[rb * 64 + 16 * g + eu];
#pragma unroll
    for (int g = 0; g < 4; ++g)
#pragma unroll
      for (int cc = 0; cc < 4; ++cc) pst[g][cc] = 0.f;
  }
  float cst[4] = {0.f, 0.f, 0.f, 0.f};  // persistent cell state (c1 or c2)

  const f32x4 zero4 = {0.f, 0.f, 0.f, 0.f};

#pragma unroll 1
  for (int s = 0; s < NSUP; ++s) {
    const bool g1a = isG1 && (s <= 1999);
    const bool g2a = (!isG1) && (s >= 1) && (s <= 2000);
    const bool fca = (!isG1) && (rb < 10) && (s >= 2) && (s <= 2001);
    const bool fra = (!isG1) && (rb >= 12) && (rb < 16) && (s >= 3);  // exactly 8 reducer blocks

    int cBeg = 0, cEnd = 0;
    if (g1a) { cBeg = 0; cEnd = 17; }
    else if (g2a) { cBeg = 0; cEnd = fca ? 20 : 16; }
    else if (fca) { cBeg = 16; cEnd = 20; }

    const int tp = (s < 399) ? s : 399;
    const unsigned short* h1r = h1buf + ((s + 1) & 1) * 131072 + cg * 64 * 1024;  // h1[s-1]
    const unsigned short* h2r = h2buf + (s & 1) * 131072 + cg * 64 * 1024;        // h2[s-2]

    f32x4 acc[4][4];
    f32x4 facc[4];
#pragma unroll
    for (int i = 0; i < 4; ++i) {
      facc[i] = zero4;
#pragma unroll
      for (int j = 0; j < 4; ++j) acc[i][j] = zero4;
    }

    auto issue = [&](int c) {
      const unsigned char* Ab; size_t Astr; int Amask = 63;
      const unsigned char* Bb; size_t Bstr; bool coh;
      if (isG1) {
        if (c < 8)       { Ab = wA1 + c * 256; Astr = 2048; }
        else if (c < 16) { Ab = wA2 + (c - 8) * 256; Astr = 2048; }
        else             { Ab = wAp; Astr = 256; }
        if (c < 8)       { Bb = encB + (size_t)tp * 2048 + c * 256; Bstr = 819200; coh = false; }
        else if (c < 16) { Bb = (const unsigned char*)h1r + (c - 8) * 256; Bstr = 2048; coh = true; }
        else             { Bb = prevB + (size_t)s * 32768; Bstr = 256; coh = false; }
      } else {
        if (c < 8)       { Ab = wA1 + c * 256; Astr = 2048; }
        else if (c < 16) { Ab = wA2 + (c - 8) * 256; Astr = 2048; }
        else             { Ab = wFc + (size_t)(khf * 512 + (c - 16) * 128) * 2; Astr = 2048; Amask = 15; }
        if (c < 8)       Bb = (const unsigned char*)h1r + c * 256;
        else if (c < 16) Bb = (const unsigned char*)h2r + (c - 8) * 256;
        else             Bb = (const unsigned char*)h2r + (size_t)(khf * 512 + (c - 16) * 128) * 2;
        Bstr = 2048; coh = true;
      }
      unsigned char* lA = smem + (c & 3) * 32768 + w * 4096;
      unsigned char* lB = lA + 16384;
#pragma unroll
      for (int a = 0; a < 4; ++a) {
        int p = a * 1024 + l * 16;
        int rr = p >> 6, cb = p & 63;
        int kb = cb ^ (((rr >> 1) & 3) << 4);  // pre-swizzled source (involution)
        const unsigned char* ga = Ab + (size_t)(rr & Amask) * Astr + w * 64 + kb;
        const unsigned char* gb = Bb + (size_t)rr * Bstr + w * 64 + kb;
        __builtin_amdgcn_global_load_lds((GPTR)ga, (LPTR)(lA + a * 1024), 16, 0, 0);
        if (coh) __builtin_amdgcn_global_load_lds((GPTR)gb, (LPTR)(lB + a * 1024), 16, 0, 17);
        else     __builtin_amdgcn_global_load_lds((GPTR)gb, (LPTR)(lB + a * 1024), 16, 0, 0);
      }
    };

    auto computeC = [&](int c) {
      const unsigned char* lA = smem + (c & 3) * 32768 + w * 4096;
      const unsigned char* lB = lA + 16384;
      bf16x8 av[4], bv[4];
#pragma unroll
      for (int i = 0; i < 4; ++i) {
        av[i] = *(const bf16x8*)(lA + i * 1024 + laneOff);
        bv[i] = *(const bf16x8*)(lB + i * 1024 + laneOff);
      }
      if (isG1 || c < 16) {
#pragma unroll
        for (int i = 0; i < 4; ++i)
#pragma unroll
          for (int j = 0; j < 4; ++j)
            acc[i][j] = __builtin_amdgcn_mfma_f32_16x16x32_bf16(av[i], bv[j], acc[i][j], 0, 0, 0);
      } else {
#pragma unroll
        for (int j = 0; j < 4; ++j)
          facc[j] = __builtin_amdgcn_mfma_f32_16x16x32_bf16(av[0], bv[j], facc[j], 0, 0, 0);
      }
    };

    if (cEnd > cBeg) {
#pragma unroll 1
      for (int pc = cBeg; pc < cEnd && pc < cBeg + 4; ++pc) issue(pc);
    }

    // fc reduce + output (data from s-1) — overlapped with staging DMAs in flight
    if (fra) {
      const int t0 = s - 3;
      const float* FP = fcpart + ((s - 1) & 1) * 24576;
      const int brank = (rb - 12) * 2 + cg;   // 0..7
#pragma unroll
      for (int q = 0; q < 5; ++q) {
        int o = brank * 1280 + tid * 5 + q;   // 0..10239
        int m = o >> 7, n = o & 127;
        float v = __hip_atomic_load(FP + m * 128 + n, __ATOMIC_RELAXED, __HIP_MEMORY_SCOPE_AGENT) +
                  __hip_atomic_load(FP + 12288 + m * 128 + n, __ATOMIC_RELAXED, __HIP_MEMORY_SCOPE_AGENT) +
                  fc_b[m];
        out[(size_t)(n * 80 + m) * 2000 + t0] = v;
      }
    }

    if (cEnd > cBeg) {
#pragma unroll 1
      for (int c = cBeg; c < cEnd; ++c) {
        int rem = cEnd - 1 - c;
        if (rem >= 3)      asm volatile("s_waitcnt vmcnt(24)" ::: "memory");
        else if (rem == 2) asm volatile("s_waitcnt vmcnt(16)" ::: "memory");
        else if (rem == 1) asm volatile("s_waitcnt vmcnt(8)" ::: "memory");
        else               asm volatile("s_waitcnt vmcnt(0)" ::: "memory");
        __builtin_amdgcn_sched_barrier(0);
        computeC(c);
        if (c + 4 < cEnd) issue(c + 4);
      }
    }

    // ---- main epilogue: cross-wave K reduction + fused LSTM pointwise ----
    if (g1a || g2a) {
      __syncthreads();
      float* red = (float*)smem;  // [4 waves][64 rows][stride 68]
      const int rwo = w * 4352;
#pragma unroll
      for (int i = 0; i < 4; ++i)
#pragma unroll
        for (int q = 0; q < 4; ++q) {
          int row = 16 * i + ((l >> 4) << 2) + q;
#pragma unroll
          for (int j = 0; j < 4; ++j)
            red[rwo + row * 68 + 16 * j + (l & 15)] = acc[i][j][q];
        }
      __syncthreads();
      float gate[4][4];
#pragma unroll
      for (int g = 0; g < 4; ++g) {
        f32x4 ss = zero4;
#pragma unroll
        for (int ww = 0; ww < 4; ++ww)
          ss += *(const f32x4*)&red[ww * 4352 + (16 * g + eu) * 68 + ec0];
#pragma unroll
        for (int cc = 0; cc < 4; ++cc) gate[g][cc] = ss[cc];
      }
      unsigned short* hw_ = g1a ? (h1buf + (s & 1) * 131072) : (h2buf + ((s - 1) & 1) * 131072);
      const int urow = rb * 16 + eu;
#pragma unroll
      for (int cc = 0; cc < 4; ++cc) {
        float gi = gate[0][cc] + (isG1 ? pst[0][cc] : b2r[0]);
        float gf = gate[1][cc] + (isG1 ? pst[1][cc] : b2r[1]);
        float gg = gate[2][cc] + (isG1 ? pst[2][cc] : b2r[2]);
        float go = gate[3][cc] + (isG1 ? pst[3][cc] : b2r[3]);
        float ci = sigm(gi), cf = sigm(gf), cgt = tanh_(gg), co = sigm(go);
        cst[cc] = cf * cst[cc] + ci * cgt;
        float hv = co * tanh_(cst[cc]);
        int ncol = cg * 64 + ec0 + cc;
        unsigned v32 = (unsigned)f2bf(hv);
        const unsigned short* ha = &hw_[(size_t)ncol * 1024 + urow];
        asm volatile("global_store_short %0, %1, off sc0 sc1" ::"v"(ha), "v"(v32) : "memory");
      }
    }

    // ---- fc partial epilogue ----
    if (fca) {
      __syncthreads();
      float* fr = (float*)smem;  // [4 waves][16 rows][stride 68]
      const int fwo = w * 1088;
#pragma unroll
      for (int q = 0; q < 4; ++q) {
        int row = ((l >> 4) << 2) + q;
#pragma unroll
        for (int j = 0; j < 4; ++j)
          fr[fwo + row * 68 + 16 * j + (l & 15)] = facc[j][q];
      }
      __syncthreads();
      {
        int rr = tid >> 4, c0 = (tid & 15) << 2;
        f32x4 ss = zero4;
#pragma unroll
        for (int ww = 0; ww < 4; ++ww) ss += *(const f32x4*)&fr[ww * 1088 + rr * 68 + c0];
        float* FP = fcpart + (s & 1) * 24576 + khf * 12288 + (size_t)(16 * rf + rr) * 128 + cg * 64 + c0;
#pragma unroll
        for (int cc = 0; cc < 4; ++cc)
          __hip_atomic_store(FP + cc, ss[cc], __ATOMIC_RELAXED, __HIP_MEMORY_SCOPE_AGENT);
      }
    }

    // ---- global barrier (8 spread counters at MALL) ----
    asm volatile("s_waitcnt vmcnt(0)" ::: "memory");
    __syncthreads();
    if (tid == 0) {
      __hip_atomic_fetch_add(&cnts[(bid & 7) * 64], 1u, __ATOMIC_RELEASE, __HIP_MEMORY_SCOPE_AGENT);
      unsigned tgt = 256u * (unsigned)(s + 1);
      for (long it = 0; it < 2000000; ++it) {
        unsigned sum = 0;
#pragma unroll
        for (int i2 = 0; i2 < 8; ++i2)
          sum += __hip_atomic_load(&cnts[i2 * 64], __ATOMIC_RELAXED, __HIP_MEMORY_SCOPE_AGENT);
        if (sum >= tgt) break;
        __builtin_amdgcn_s_sleep(1);
      }
    }
    __syncthreads();
  }
}

// --------------------------------- launcher ---------------------------------
extern "C" void kernel_launch(void* const* d_in, const int* in_sizes, int n_in,
                              void* d_out, int out_size, void* d_ws, size_t ws_size,
                              hipStream_t stream) {
  (void)in_sizes; (void)n_in; (void)out_size;
  const float* enc  = (const float*)d_in[0];
  const float* styl = (const float*)d_in[1];
  const float* mel  = (const float*)d_in[2];
  const float* Wih1 = (const float*)d_in[3];
  const float* Whh1 = (const float*)d_in[4];
  const float* bih1 = (const float*)d_in[5];
  const float* bhh1 = (const float*)d_in[6];
  const float* Wih2 = (const float*)d_in[7];
  const float* Whh2 = (const float*)d_in[8];
  const float* bih2 = (const float*)d_in[9];
  const float* bhh2 = (const float*)d_in[10];
  const float* fcw  = (const float*)d_in[11];
  const float* fcb  = (const float*)d_in[12];
  unsigned char* ws = (unsigned char*)d_ws;
  float* out = (float*)d_out;
  if (ws_size < WS_NEED) return;  // insufficient scratch; fail loudly via validation

  hipMemsetAsync(ws + OFF_PREV, 0, (size_t)(OFF_STYLET - OFF_PREV), stream);
  k_pack_w1<<<16384, 256, 0, stream>>>(Wih1, Whh1, ws);
  k_pack_w2<<<16384, 256, 0, stream>>>(Wih2, Whh2, ws);
  k_bias2<<<16, 256, 0, stream>>>(bih2, bhh2, ws);
  k_pack_wprev<<<2048, 256, 0, stream>>>(Wih1, ws);
  k_pack_fc<<<384, 256, 0, stream>>>(fcw, ws);
  k_pack_enc<<<51200, 256, 0, stream>>>(enc, ws);
  k_styleT<<<160, 256, 0, stream>>>(styl, (float*)(ws + OFF_STYLET));
  k_pstyle<<<2048, 256, 0, stream>>>(Wih1, bih1, bhh1, (float*)(ws + OFF_STYLET), ws);
  k_pack_prev<<<dim3(32, 128), 256, 0, stream>>>(mel, ws);
  k_persist<<<256, 256, 0, stream>>>(ws, out, fcb);
}

// Round 3
// 38780.893 us; speedup vs baseline: 1.3880x; 1.3880x over previous
//
#include <hip/hip_runtime.h>
#include <hip/hip_bf16.h>
#include <stdint.h>

// ---------------------------------------------------------------------------
// Persistent-kernel LSTM decoder for MI355X — v3: weight-stationary in VGPRs.
// superphase s: g1 blocks (0..127): gates1[s] -> h1[s]
//               g2 blocks (128..255): gates2[s-1] -> h2[s-1]
//               fc (fused in g2 blocks 128..139, waves 2-3): frame[s-2] -> out
// h1/h2 cross-XCD via MALL (sc0 sc1 stores + sc0 sc1 register loads).
// Weights live in registers for the whole kernel; no LDS staging.
// ---------------------------------------------------------------------------

#define NSUP 2002

typedef __attribute__((ext_vector_type(8))) short bf16x8;
typedef __attribute__((ext_vector_type(4))) float f32x4;

// ws layout (bytes) — unchanged from v2
#define OFF_WTXT   0ull
#define OFF_WHH1   8388608ull
#define OFF_WPREV  16777216ull
#define OFF_WIH2   17825792ull
#define OFF_WHH2   26214400ull
#define OFF_FCW    34603008ull
#define OFF_BIAS2  34799616ull
#define OFF_PSTYLE 34816000ull
#define OFF_ENC    36913152ull
#define OFF_PREV   141770752ull
#define OFF_H1     207306752ull
#define OFF_H2     207831040ull
#define OFF_FCPART 208355328ull
#define OFF_CNT    208551936ull
#define OFF_STYLET 208553984ull
#define WS_NEED    208717824ull

__device__ __forceinline__ unsigned short f2bf(float f) {
  __hip_bfloat16 b = __float2bfloat16(f);
  return *reinterpret_cast<unsigned short*>(&b);
}
__device__ __forceinline__ float sigm(float x) { return 1.f / (1.f + __expf(-x)); }
__device__ __forceinline__ float tanh_(float x) {
  x = fminf(15.f, fmaxf(-15.f, x));
  float e = __expf(2.f * x);
  return (e - 1.f) / (e + 1.f);
}
__device__ __forceinline__ int origRow(int rp) {
  return ((rp >> 4) & 3) * 1024 + (rp >> 6) * 16 + (rp & 15);
}

#define VMW(n) asm volatile("s_waitcnt vmcnt(" #n ")" ::: "memory")

__device__ __forceinline__ void ldx4_coh(bf16x8& d, const void* p) {
  asm volatile("global_load_dwordx4 %0, %1, off sc0 sc1" : "=v"(d) : "v"(p));
}
__device__ __forceinline__ void ldx4_nc(bf16x8& d, const void* p) {
  asm volatile("global_load_dwordx4 %0, %1, off" : "=v"(d) : "v"(p));
}

// ------------------------------- pack kernels -------------------------------
__global__ void k_pack_w1(const float* __restrict__ wih1, const float* __restrict__ whh1,
                          unsigned char* __restrict__ ws) {
  int idx = blockIdx.x * 256 + threadIdx.x;            // 4096*1024
  int rp = idx >> 10, k = idx & 1023;
  int orig = origRow(rp);
  ((unsigned short*)(ws + OFF_WTXT))[idx] = f2bf(wih1[(size_t)orig * 1424 + k]);
  ((unsigned short*)(ws + OFF_WHH1))[idx] = f2bf(whh1[(size_t)orig * 1024 + k]);
}
__global__ void k_pack_w2(const float* __restrict__ wih2, const float* __restrict__ whh2,
                          unsigned char* __restrict__ ws) {
  int idx = blockIdx.x * 256 + threadIdx.x;
  int rp = idx >> 10, k = idx & 1023;
  int orig = origRow(rp);
  ((unsigned short*)(ws + OFF_WIH2))[idx] = f2bf(wih2[(size_t)orig * 1024 + k]);
  ((unsigned short*)(ws + OFF_WHH2))[idx] = f2bf(whh2[(size_t)orig * 1024 + k]);
}
__global__ void k_bias2(const float* __restrict__ bih2, const float* __restrict__ bhh2,
                        unsigned char* __restrict__ ws) {
  int rp = blockIdx.x * 256 + threadIdx.x;
  if (rp >= 4096) return;
  int orig = origRow(rp);
  ((float*)(ws + OFF_BIAS2))[rp] = bih2[orig] + bhh2[orig];
}
__global__ void k_pack_wprev(const float* __restrict__ wih1, unsigned char* __restrict__ ws) {
  int idx = blockIdx.x * 256 + threadIdx.x;            // 4096*128
  int rp = idx >> 7, k = idx & 127;
  int orig = origRow(rp);
  ((unsigned short*)(ws + OFF_WPREV))[idx] =
      (k < 80) ? f2bf(wih1[(size_t)orig * 1424 + 1344 + k]) : (unsigned short)0;
}
__global__ void k_pack_fc(const float* __restrict__ fcw, unsigned char* __restrict__ ws) {
  int idx = blockIdx.x * 256 + threadIdx.x;            // 96*1024
  int r = idx >> 10, k = idx & 1023;
  ((unsigned short*)(ws + OFF_FCW))[idx] =
      (r < 80) ? f2bf(fcw[(size_t)r * 1024 + k]) : (unsigned short)0;
}
__global__ void k_pack_enc(const float* __restrict__ enc, unsigned char* __restrict__ ws) {
  size_t i = (size_t)blockIdx.x * 256 + threadIdx.x;   // 13,107,200 float4's
  float4 v = ((const float4*)enc)[i];
  union { unsigned short u[4]; unsigned long long ll; } z;
  z.u[0] = f2bf(v.x); z.u[1] = f2bf(v.y); z.u[2] = f2bf(v.z); z.u[3] = f2bf(v.w);
  ((unsigned long long*)(ws + OFF_ENC))[i] = z.ll;
}
__global__ void k_styleT(const float* __restrict__ style, float* __restrict__ sT) {
  int idx = blockIdx.x * 256 + threadIdx.x;            // 320*128
  int j = idx >> 7, n = idx & 127;
  sT[idx] = style[n * 320 + j];
}
__global__ void k_pstyle(const float* __restrict__ wih1, const float* __restrict__ bih1,
                         const float* __restrict__ bhh1, const float* __restrict__ sT,
                         unsigned char* __restrict__ ws) {
  int n = threadIdx.x & 127, rsub = threadIdx.x >> 7;
  int rp = blockIdx.x * 2 + rsub;
  int orig = origRow(rp);
  const float* wr = wih1 + (size_t)orig * 1424 + 1024;
  float a0 = 0.f, a1 = 0.f, a2 = 0.f, a3 = 0.f;
  for (int j = 0; j < 320; j += 4) {
    a0 += wr[j + 0] * sT[(j + 0) * 128 + n];
    a1 += wr[j + 1] * sT[(j + 1) * 128 + n];
    a2 += wr[j + 2] * sT[(j + 2) * 128 + n];
    a3 += wr[j + 3] * sT[(j + 3) * 128 + n];
  }
  ((float*)(ws + OFF_PSTYLE))[rp * 128 + n] = (a0 + a1) + (a2 + a3) + bih1[orig] + bhh1[orig];
}
__global__ void k_pack_prev(const float* __restrict__ mel, unsigned char* __restrict__ ws) {
  __shared__ unsigned short pl[64][80];
  int b = blockIdx.y, tt0 = blockIdx.x * 64;
  int tid = threadIdx.x;
  int ttl = tid & 63, mi = tid >> 6;
  for (int m = mi; m < 80; m += 4) {
    int tau = tt0 + ttl;
    if (tau <= 1998) pl[ttl][m] = f2bf(mel[((size_t)b * 80 + m) * 2000 + tau]);
  }
  __syncthreads();
  unsigned short* pv = (unsigned short*)(ws + OFF_PREV);
  for (int idx = tid; idx < 64 * 80; idx += 256) {
    int t2 = idx / 80, m2 = idx % 80;
    int tau = tt0 + t2;
    if (tau <= 1998) pv[((size_t)(tau + 1) * 128 + b) * 128 + m2] = pl[t2][m2];
  }
}

// ------------------------------ persistent kernel ---------------------------
__global__ __launch_bounds__(256, 1) void k_persist(unsigned char* __restrict__ ws,
                                                    float* __restrict__ out,
                                                    const float* __restrict__ fc_b) {
  __shared__ float red[4][64][68];    // 69632 B  cross-wave K reduction
  __shared__ float fcred[2][16][68];  // 8704 B   fc partials (waves 2,3)

  const int tid = threadIdx.x, bid = blockIdx.x;
  const int w = tid >> 6, l = tid & 63;
  const int r15 = l & 15, khi = l >> 4;
  const bool isG1 = bid < 128;
  const int lb = bid & 127, rb = lb >> 1, cg = lb & 1;
  const bool fcB = (!isG1) && (lb < 12);
  const bool fcact = fcB && (w >= 2);     // waves that carry fc loads/MFMA
  const int u6 = lb >> 1;                 // fc row-block (0..5) for fc blocks

  unsigned* cnts = (unsigned*)(ws + OFF_CNT);

  // ---------------- resident A fragments ----------------
  // g1: t0..15 from (w<2 ? WTXT[k 512w..] : WHH1[k 512(w-2)..]); t16 from WPREV[k 32w..]
  // g2: t0..15 from (w<2 ? WIH2[k 512w..] : WHH2[k 512(w-2)..])
  bf16x8 avr[4][17];
  {
    const unsigned char* Wmain =
        ws + (isG1 ? (w < 2 ? OFF_WTXT : OFF_WHH1) : (w < 2 ? OFF_WIH2 : OFF_WHH2)) +
        (size_t)(w & 1) * 1024;  // +512 k-elems
#pragma unroll
    for (int i = 0; i < 4; ++i) {
      const unsigned char* rowp = Wmain + ((size_t)(rb * 64 + 16 * i + r15)) * 2048 + khi * 16;
#pragma unroll
      for (int t = 0; t < 16; ++t) avr[i][t] = *(const bf16x8*)(rowp + t * 64);
      if (isG1)
        avr[i][16] = *(const bf16x8*)(ws + OFF_WPREV +
                                      ((size_t)(rb * 64 + 16 * i + r15)) * 256 + w * 64 + khi * 16);
    }
  }

  // ---------------- per-lane B column offsets ----------------
  // col(j) = cg*64 + 16j + r15 ; within-k lane offset khi*16 bytes
  size_t encoff[4], hoff[4], prevoff[4];
#pragma unroll
  for (int j = 0; j < 4; ++j) {
    int col = cg * 64 + 16 * j + r15;
    encoff[j] = (size_t)col * 819200 + (size_t)(w & 1) * 1024 + khi * 16;       // w<2 only
    hoff[j]   = (size_t)col * 2048 + (size_t)(w & 1) * 1024 + khi * 16;         // h1/h2 slices
    prevoff[j] = (size_t)col * 256 + w * 64 + khi * 16;
  }
  const unsigned char* fccol = ws + OFF_FCW + ((size_t)(16 * u6 + r15)) * 2048 +
                               (size_t)(w & 1) * 1024 + khi * 16;               // fc waves

  // ---------------- epilogue constants ----------------
  const int ecol = tid & 63, quad = tid >> 6;  // epilogue thread mapping
  float pstb[4][4];   // g1: style+bias ; g2: bias2 broadcast per gate/unit
#pragma unroll
  for (int g = 0; g < 4; ++g)
#pragma unroll
    for (int u = 0; u < 4; ++u) {
      int rloc = 16 * g + quad * 4 + u;
      if (isG1)
        pstb[g][u] = ((const float*)(ws + OFF_PSTYLE))[(size_t)(rb * 64 + rloc) * 128 + cg * 64 + ecol];
      else
        pstb[g][u] = ((const float*)(ws + OFF_BIAS2))[rb * 64 + rloc];
    }
  float fcbr[4];
#pragma unroll
  for (int q = 0; q < 4; ++q) {
    int m = u6 * 16 + quad * 4 + q;
    fcbr[q] = (fcB && m < 80) ? fc_b[m] : 0.f;
  }
  float cst[4] = {0.f, 0.f, 0.f, 0.f};
  const f32x4 zero4 = {0.f, 0.f, 0.f, 0.f};

#pragma unroll 1
  for (int s = 0; s < NSUP; ++s) {
    const bool g1a = isG1 && (s <= 1999);
    const bool g2a = (!isG1) && (s >= 1) && (s <= 2000);
    const bool fca = fcB && (s >= 2) && (s <= 2001);
    const bool g2run = g2a || fca;

    const unsigned char* h1rd = ws + OFF_H1 + (size_t)((s + 1) & 1) * 262144;  // h1[s-1]
    const unsigned char* h2rd = ws + OFF_H2 + (size_t)(s & 1) * 262144;        // h2[s-2]

    if (g1a) {
      // ---------------- gates1 K-loop (T=17) ----------------
      f32x4 acc[4][4];
#pragma unroll
      for (int i = 0; i < 4; ++i)
#pragma unroll
        for (int j = 0; j < 4; ++j) acc[i][j] = zero4;

      const int tp = (s < 399) ? s : 399;
      const unsigned char* bp[4];
      const unsigned char* pp[4];
#pragma unroll
      for (int j = 0; j < 4; ++j) {
        if (w < 2) bp[j] = ws + OFF_ENC + encoff[j] + (size_t)tp * 2048;
        else       bp[j] = h1rd + hoff[j];
        pp[j] = ws + OFF_PREV + (size_t)s * 32768 + prevoff[j];
      }
      bf16x8 bvr[4][4];

      auto ISS = [&](int t) __attribute__((always_inline)) {
        if (t < 16) {
          if (w < 2) {
#pragma unroll
            for (int j = 0; j < 4; ++j) { ldx4_nc(bvr[t & 3][j], bp[j]); bp[j] += 64; }
          } else {
#pragma unroll
            for (int j = 0; j < 4; ++j) { ldx4_coh(bvr[t & 3][j], bp[j]); bp[j] += 64; }
          }
        } else {
#pragma unroll
          for (int j = 0; j < 4; ++j) ldx4_nc(bvr[t & 3][j], pp[j]);
        }
      };

      ISS(0); ISS(1); ISS(2); ISS(3);
#pragma unroll
      for (int t = 0; t < 17; ++t) {
        if (t <= 13) VMW(12);
        else if (t == 14) VMW(8);
        else if (t == 15) VMW(4);
        else VMW(0);
        __builtin_amdgcn_sched_barrier(0);
#pragma unroll
        for (int i = 0; i < 4; ++i)
#pragma unroll
          for (int j = 0; j < 4; ++j)
            acc[i][j] = __builtin_amdgcn_mfma_f32_16x16x32_bf16(avr[i][t], bvr[t & 3][j],
                                                                acc[i][j], 0, 0, 0);
        if (t <= 12) ISS(t + 4);
      }

      // ---------------- epilogue: reduce + LSTM + h1 store ----------------
#pragma unroll
      for (int i = 0; i < 4; ++i)
#pragma unroll
        for (int j = 0; j < 4; ++j)
#pragma unroll
          for (int q = 0; q < 4; ++q)
            red[w][16 * i + khi * 4 + q][16 * j + r15] = acc[i][j][q];
      __syncthreads();
      {
        unsigned hm[4];
#pragma unroll
        for (int u = 0; u < 4; ++u) {
          float gt[4];
#pragma unroll
          for (int g = 0; g < 4; ++g) {
            int row = 16 * g + quad * 4 + u;
            gt[g] = red[0][row][ecol] + red[1][row][ecol] + red[2][row][ecol] +
                    red[3][row][ecol] + pstb[g][u];
          }
          float ci = sigm(gt[0]), cf = sigm(gt[1]), cgt = tanh_(gt[2]), co = sigm(gt[3]);
          cst[u] = cf * cst[u] + ci * cgt;
          hm[u] = f2bf(co * tanh_(cst[u]));
        }
        unsigned long long hv = (unsigned long long)(hm[0] | (hm[1] << 16)) |
                                ((unsigned long long)(hm[2] | (hm[3] << 16)) << 32);
        const void* ha = ws + OFF_H1 + (size_t)(s & 1) * 262144 +
                         (size_t)(cg * 64 + ecol) * 2048 + (size_t)(rb * 16 + quad * 4) * 2;
        asm volatile("global_store_dwordx2 %0, %1, off sc0 sc1" ::"v"(ha), "v"(hv) : "memory");
      }
    } else if (g2run) {
      // ---------------- gates2 (+fc) K-loop (T=16) ----------------
      f32x4 acc[4][4];
      f32x4 facc[4];
#pragma unroll
      for (int i = 0; i < 4; ++i) {
        facc[i] = zero4;
#pragma unroll
        for (int j = 0; j < 4; ++j) acc[i][j] = zero4;
      }
      const unsigned char* bp[4];
#pragma unroll
      for (int j = 0; j < 4; ++j) bp[j] = (w < 2 ? h1rd : h2rd) + hoff[j];
      const unsigned char* fp = fccol;
      bf16x8 bvr[4][4];
      bf16x8 fcav[4];

      auto ISS = [&](int t) __attribute__((always_inline)) {
#pragma unroll
        for (int j = 0; j < 4; ++j) { ldx4_coh(bvr[t & 3][j], bp[j]); bp[j] += 64; }
        if (fcact) { ldx4_nc(fcav[t & 3], fp); fp += 64; }
      };

      ISS(0); ISS(1); ISS(2); ISS(3);
#pragma unroll
      for (int t = 0; t < 16; ++t) {
        if (t <= 12) { if (fcact) VMW(15); else VMW(12); }
        else if (t == 13) { if (fcact) VMW(10); else VMW(8); }
        else if (t == 14) { if (fcact) VMW(5); else VMW(4); }
        else VMW(0);
        __builtin_amdgcn_sched_barrier(0);
        if (g2a) {
#pragma unroll
          for (int i = 0; i < 4; ++i)
#pragma unroll
            for (int j = 0; j < 4; ++j)
              acc[i][j] = __builtin_amdgcn_mfma_f32_16x16x32_bf16(avr[i][t], bvr[t & 3][j],
                                                                  acc[i][j], 0, 0, 0);
        }
        if (fcact && fca) {
#pragma unroll
          for (int j = 0; j < 4; ++j)
            facc[j] = __builtin_amdgcn_mfma_f32_16x16x32_bf16(fcav[t & 3], bvr[t & 3][j],
                                                              facc[j], 0, 0, 0);
        }
        if (t <= 11) ISS(t + 4);
      }

      // ---------------- epilogues ----------------
      if (g2a) {
#pragma unroll
        for (int i = 0; i < 4; ++i)
#pragma unroll
          for (int j = 0; j < 4; ++j)
#pragma unroll
            for (int q = 0; q < 4; ++q)
              red[w][16 * i + khi * 4 + q][16 * j + r15] = acc[i][j][q];
      }
      if (fcact && fca) {
#pragma unroll
        for (int j = 0; j < 4; ++j)
#pragma unroll
          for (int q = 0; q < 4; ++q)
            fcred[w - 2][khi * 4 + q][16 * j + r15] = facc[j][q];
      }
      __syncthreads();
      if (g2a) {
        unsigned hm[4];
#pragma unroll
        for (int u = 0; u < 4; ++u) {
          float gt[4];
#pragma unroll
          for (int g = 0; g < 4; ++g) {
            int row = 16 * g + quad * 4 + u;
            gt[g] = red[0][row][ecol] + red[1][row][ecol] + red[2][row][ecol] +
                    red[3][row][ecol] + pstb[g][u];
          }
          float ci = sigm(gt[0]), cf = sigm(gt[1]), cgt = tanh_(gt[2]), co = sigm(gt[3]);
          cst[u] = cf * cst[u] + ci * cgt;
          hm[u] = f2bf(co * tanh_(cst[u]));
        }
        unsigned long long hv = (unsigned long long)(hm[0] | (hm[1] << 16)) |
                                ((unsigned long long)(hm[2] | (hm[3] << 16)) << 32);
        const void* ha = ws + OFF_H2 + (size_t)((s + 1) & 1) * 262144 +
                         (size_t)(cg * 64 + ecol) * 2048 + (size_t)(rb * 16 + quad * 4) * 2;
        asm volatile("global_store_dwordx2 %0, %1, off sc0 sc1" ::"v"(ha), "v"(hv) : "memory");
      }
      if (fca) {
        const int t0 = s - 2;
#pragma unroll
        for (int q = 0; q < 4; ++q) {
          int m = u6 * 16 + quad * 4 + q;
          float v = fcred[0][quad * 4 + q][ecol] + fcred[1][quad * 4 + q][ecol] + fcbr[q];
          if (m < 80) out[((size_t)(cg * 64 + ecol) * 80 + m) * 2000 + t0] = v;
        }
      }
    }

    // ---- global barrier (8 spread counters at MALL) ----
    asm volatile("s_waitcnt vmcnt(0)" ::: "memory");
    __syncthreads();
    if (tid == 0) {
      __hip_atomic_fetch_add(&cnts[(bid & 7) * 64], 1u, __ATOMIC_RELEASE, __HIP_MEMORY_SCOPE_AGENT);
      unsigned tgt = 256u * (unsigned)(s + 1);
      for (long it = 0; it < 2000000; ++it) {
        unsigned sum = 0;
#pragma unroll
        for (int i2 = 0; i2 < 8; ++i2)
          sum += __hip_atomic_load(&cnts[i2 * 64], __ATOMIC_RELAXED, __HIP_MEMORY_SCOPE_AGENT);
        if (sum >= tgt) break;
        __builtin_amdgcn_s_sleep(1);
      }
    }
    __syncthreads();
  }
}

// --------------------------------- launcher ---------------------------------
extern "C" void kernel_launch(void* const* d_in, const int* in_sizes, int n_in,
                              void* d_out, int out_size, void* d_ws, size_t ws_size,
                              hipStream_t stream) {
  (void)in_sizes; (void)n_in; (void)out_size;
  const float* enc  = (const float*)d_in[0];
  const float* styl = (const float*)d_in[1];
  const float* mel  = (const float*)d_in[2];
  const float* Wih1 = (const float*)d_in[3];
  const float* Whh1 = (const float*)d_in[4];
  const float* bih1 = (const float*)d_in[5];
  const float* bhh1 = (const float*)d_in[6];
  const float* Wih2 = (const float*)d_in[7];
  const float* Whh2 = (const float*)d_in[8];
  const float* bih2 = (const float*)d_in[9];
  const float* bhh2 = (const float*)d_in[10];
  const float* fcw  = (const float*)d_in[11];
  const float* fcb  = (const float*)d_in[12];
  unsigned char* ws = (unsigned char*)d_ws;
  float* out = (float*)d_out;
  if (ws_size < WS_NEED) return;

  hipMemsetAsync(ws + OFF_PREV, 0, (size_t)(OFF_STYLET - OFF_PREV), stream);
  k_pack_w1<<<16384, 256, 0, stream>>>(Wih1, Whh1, ws);
  k_pack_w2<<<16384, 256, 0, stream>>>(Wih2, Whh2, ws);
  k_bias2<<<16, 256, 0, stream>>>(bih2, bhh2, ws);
  k_pack_wprev<<<2048, 256, 0, stream>>>(Wih1, ws);
  k_pack_fc<<<384, 256, 0, stream>>>(fcw, ws);
  k_pack_enc<<<51200, 256, 0, stream>>>(enc, ws);
  k_styleT<<<160, 256, 0, stream>>>(styl, (float*)(ws + OFF_STYLET));
  k_pstyle<<<2048, 256, 0, stream>>>(Wih1, bih1, bhh1, (float*)(ws + OFF_STYLET), ws);
  k_pack_prev<<<dim3(32, 128), 256, 0, stream>>>(mel, ws);
  k_persist<<<256, 256, 0, stream>>>(ws, out, fcb);
}